// Round 10
// baseline (501.154 us; speedup 1.0000x reference)
//
#include <hip/hip_runtime.h>
#include <hip/hip_bf16.h>

#define T_LEN 2048
#define HID_DIM 2048
#define NH 16
#define NKV 2
#define HD 256
#define ROT 64
#define EPS_F 1e-6f
#define SCALE_F 0.0625f   // 256^-0.5
#define THETA_F 10000000.0f

typedef __bf16 bf16x8 __attribute__((ext_vector_type(8)));
typedef float floatx4 __attribute__((ext_vector_type(4)));

__device__ __forceinline__ unsigned short f2bf(float x) {
  unsigned int u = __float_as_uint(x);
  unsigned int rounding = 0x7FFFu + ((u >> 16) & 1u);
  return (unsigned short)((u + rounding) >> 16);
}
__device__ __forceinline__ float bf2f(unsigned short u) {
  return __uint_as_float(((unsigned int)u) << 16);
}
__device__ __forceinline__ floatx4 mfma16(bf16x8 a, bf16x8 b, floatx4 c) {
  return __builtin_amdgcn_mfma_f32_16x16x32_bf16(a, b, c, 0, 0, 0);
}
// async global->LDS DMA, 16B/lane: lds dest = wave-uniform base + lane*16
__device__ __forceinline__ void gl_lds16(const unsigned short* g, unsigned short* l) {
  __builtin_amdgcn_global_load_lds(
      (const __attribute__((address_space(1))) unsigned int*)g,
      (__attribute__((address_space(3))) unsigned int*)l, 16, 0, 0);
}

// ---------------- merged fp32 -> bf16 conversion + RoPE table ----------------
// Segments 0-4: f4-vectorized cast (7864320 float4). Tail blocks (i >=
// 7864320): one (t,i) RoPE cos/sin entry each -- 65,536 trig sets, 36x fewer
// than per-head recompute; folded here to save a launch.
__global__ __launch_bounds__(256) void cvt_all(
    const float* __restrict__ hs, const float* __restrict__ wq,
    const float* __restrict__ wk, const float* __restrict__ wv,
    const float* __restrict__ wo, unsigned short* __restrict__ hsb,
    unsigned short* __restrict__ qkvwb, unsigned short* __restrict__ wob,
    const int* __restrict__ pos, float2* __restrict__ tab) {
  int i = blockIdx.x * 256 + threadIdx.x;
  if (i >= 7864320) {
    const int tid = i - 7864320;  // t*32 + fi
    const int t = tid >> 5, fi = tid & 31;
    // theta^(-fi/32) = 2^(-fi*log2(theta)/32), log2(1e7)=23.2534966642
    const float fr = (float)pos[t] * exp2f(-(float)fi * (23.2534966642f / 32.0f));
    tab[tid] = make_float2(cosf(fr), sinf(fr));
    return;
  }
  const float4* s4;
  ushort4* d4;
  int j;
  if (i < 1048576) { s4 = (const float4*)hs; d4 = (ushort4*)hsb; j = i; }
  else if (i < 5242880) { s4 = (const float4*)wq; d4 = (ushort4*)qkvwb; j = i - 1048576; }
  else if (i < 5505024) { s4 = (const float4*)wk; d4 = (ushort4*)qkvwb + 4194304; j = i - 5242880; }
  else if (i < 5767168) { s4 = (const float4*)wv; d4 = (ushort4*)qkvwb + 4456448; j = i - 5505024; }
  else { s4 = (const float4*)wo; d4 = (ushort4*)wob; j = i - 5767168; }
  float4 v = s4[j];
  ushort4 o;
  o.x = f2bf(v.x); o.y = f2bf(v.y); o.z = f2bf(v.z); o.w = f2bf(v.w);
  d4[j] = o;
}

// ---------------- bf16 GEMM: C[M,N] = A[M,K] * B[N,K]^T ----------------
// ld = row stride of A and B (elements); Ksub = K-range per z-slice.
// blockIdx.z selects K-slice [z*Ksub, (z+1)*Ksub); fp32 path writes partial
// z to Cv + z*M*N (split-K for TLP when M/128 * N/128 < 2*256 CUs).
// 2-phase double-buffered staging: stage tile k+1 into buf^1 BEFORE computing
// tile k from buf, one barrier per iteration.
// vTout (bf16 path only): blocks with n0 >= 8704 write their output
// TRANSPOSED to vTout[(col-8704)*T + row] (fused V transpose).
__global__ __launch_bounds__(256) void gemm_bf16_bt(
    const unsigned short* __restrict__ A,
    const unsigned short* __restrict__ B,
    void* __restrict__ Cv, int M, int N, int ld, int Ksub, int c_bf16,
    unsigned short* __restrict__ vTout) {
  __shared__ alignas(16) unsigned short As[2][128 * 32];
  __shared__ alignas(16) unsigned short Bs[2][128 * 32];
  const int tid = threadIdx.x;
  const int m0 = blockIdx.y * 128;
  const int n0 = blockIdx.x * 128;
  const int koff = blockIdx.z * Ksub;
  const int lane = tid & 63;
  const int wave = tid >> 6;
  const int wm = (wave >> 1) * 64;
  const int wn = (wave & 1) * 64;
  const int lrow = lane & 15;
  const int kgrp = lane >> 4;

  const unsigned short* aG = A + (size_t)(m0 + wave * 32 + (lane >> 2)) * ld + (lane & 3) * 8 + koff;
  const unsigned short* bG = B + (size_t)(n0 + wave * 32 + (lane >> 2)) * ld + (lane & 3) * 8 + koff;

  auto stage = [&](int k0, int b) {
    gl_lds16(aG + k0, &As[b][(wave * 32) * 32]);
    gl_lds16(aG + (size_t)16 * ld + k0, &As[b][(wave * 32 + 16) * 32]);
    gl_lds16(bG + k0, &Bs[b][(wave * 32) * 32]);
    gl_lds16(bG + (size_t)16 * ld + k0, &Bs[b][(wave * 32 + 16) * 32]);
  };

  floatx4 acc[4][4];
#pragma unroll
  for (int i = 0; i < 4; i++)
#pragma unroll
    for (int j = 0; j < 4; j++) acc[i][j] = floatx4{0.f, 0.f, 0.f, 0.f};

  stage(0, 0);
  __syncthreads();  // buf0 ready (vmcnt(0) drain emitted before barrier)
  int cur = 0;
  for (int k0 = 0; k0 < Ksub; k0 += 32) {
    if (k0 + 32 < Ksub) stage(k0 + 32, cur ^ 1);  // in flight during compute
    bf16x8 af[4], bfr[4];
#pragma unroll
    for (int i = 0; i < 4; i++)
      af[i] = *reinterpret_cast<const bf16x8*>(&As[cur][(wm + i * 16 + lrow) * 32 + kgrp * 8]);
#pragma unroll
    for (int j = 0; j < 4; j++)
      bfr[j] = *reinterpret_cast<const bf16x8*>(&Bs[cur][(wn + j * 16 + lrow) * 32 + kgrp * 8]);
#pragma unroll
    for (int i = 0; i < 4; i++)
#pragma unroll
      for (int j = 0; j < 4; j++)
        acc[i][j] = mfma16(af[i], bfr[j], acc[i][j]);
    __syncthreads();  // drains next-tile DMA; readers of cur are done (lgkmcnt0)
    cur ^= 1;
  }

  if (c_bf16) {
    unsigned short* C = (unsigned short*)Cv;
    const bool vtile = (vTout != nullptr) && (n0 >= 8704);  // block-uniform
#pragma unroll
    for (int i = 0; i < 4; i++) {
      int row = m0 + wm + i * 16 + kgrp * 4;
#pragma unroll
      for (int j = 0; j < 4; j++) {
        int col = n0 + wn + j * 16 + lrow;
        if (vtile) {
          unsigned short* vrow = vTout + (size_t)(col - 8704) * T_LEN + row;
#pragma unroll
          for (int r = 0; r < 4; r++) vrow[r] = f2bf(acc[i][j][r]);
        } else {
#pragma unroll
          for (int r = 0; r < 4; r++)
            C[(size_t)(row + r) * N + col] = f2bf(acc[i][j][r]);
        }
      }
    }
  } else {
    float* C = (float*)Cv + (size_t)blockIdx.z * M * N;
#pragma unroll
    for (int i = 0; i < 4; i++) {
      int row = m0 + wm + i * 16 + kgrp * 4;
#pragma unroll
      for (int j = 0; j < 4; j++) {
        int col = n0 + wn + j * 16 + lrow;
#pragma unroll
        for (int r = 0; r < 4; r++)
          C[(size_t)(row + r) * N + col] = acc[i][j][r];
      }
    }
  }
}

// ---------------- sum of 2 split-K fp32 partials ----------------
__global__ __launch_bounds__(256) void add_out(
    const float* __restrict__ p, float* __restrict__ out, int n4) {
  int i = blockIdx.x * 256 + threadIdx.x;  // float4 index
  if (i >= n4) return;
  float4 a = ((const float4*)p)[i];
  float4 b = ((const float4*)p)[i + n4];
  float4 o;
  o.x = a.x + b.x; o.y = a.y + b.y; o.z = a.z + b.z; o.w = a.w + b.w;
  ((float4*)out)[i] = o;
}

// ---------------- fused RMSNorm + partial RoPE, wave-local, table-driven ----------------
// One WAVE per (t, head): 64 lanes x 4 elems (d = lane*4..lane*4+3), ushort4
// loads, pure shfl reduction -- no LDS, no __syncthreads, no on-device trig.
// grid (T, 5): y<4 -> Q heads y*4+wave; y==4 -> K kv-heads on waves 0,1.
// RoPE: lane's 4 elems are on the same side of the 32-split; partner
// (d +/- 32) lives in lane^8 (lanes 0..15 only, all active for the shfl).
__global__ __launch_bounds__(256) void norm_rope_fused(
    const unsigned short* __restrict__ qkv, const float* __restrict__ qw,
    const float* __restrict__ kw, const float2* __restrict__ tab,
    unsigned short* __restrict__ qbf, unsigned short* __restrict__ kbf) {
  const int t = blockIdx.x;
  const int y = blockIdx.y;
  const int wv = threadIdx.x >> 6;
  const int lane = threadIdx.x & 63;
  const unsigned short* in;
  const float* w;
  unsigned short* outp;
  if (y < 4) {
    const int h = y * 4 + wv;
    in = qkv + (size_t)t * 9216 + h * 512;
    w = qw;
    outp = qbf + (size_t)t * (NH * HD) + h * HD;
  } else {
    if (wv >= NKV) return;
    in = qkv + (size_t)t * 9216 + 8192 + wv * HD;
    w = kw;
    outp = kbf + (size_t)t * (NKV * HD) + wv * HD;
  }
  const int d0 = lane * 4;
  ushort4 v = *reinterpret_cast<const ushort4*>(in + d0);
  float x0 = bf2f(v.x), x1 = bf2f(v.y), x2 = bf2f(v.z), x3 = bf2f(v.w);
  float ss = (x0 * x0 + x1 * x1) + (x2 * x2 + x3 * x3);
#pragma unroll
  for (int m = 32; m >= 1; m >>= 1) ss += __shfl_xor(ss, m);
  const float rms = rsqrtf(ss * (1.0f / 256.0f) + EPS_F);
  float4 w4 = *reinterpret_cast<const float4*>(w + d0);
  float y0 = x0 * rms * (1.0f + w4.x);
  float y1 = x1 * rms * (1.0f + w4.y);
  float y2 = x2 * rms * (1.0f + w4.z);
  float y3 = x3 * rms * (1.0f + w4.w);
  if (lane < 16) {
    // d0..d0+3 all < 64; partner values (d +/- 32) sit in lane^8
    float p0 = __shfl_xor(y0, 8);
    float p1 = __shfl_xor(y1, 8);
    float p2 = __shfl_xor(y2, 8);
    float p3 = __shfl_xor(y3, 8);
    const float2* trow = tab + t * 32 + (d0 & 31);  // 4 consecutive (c,s)
    float4 cs01 = *reinterpret_cast<const float4*>(trow);
    float4 cs23 = *reinterpret_cast<const float4*>(trow + 2);
    if (d0 < 32) {
      y0 = y0 * cs01.x - p0 * cs01.y;
      y1 = y1 * cs01.z - p1 * cs01.w;
      y2 = y2 * cs23.x - p2 * cs23.y;
      y3 = y3 * cs23.z - p3 * cs23.w;
    } else {
      y0 = p0 * cs01.y + y0 * cs01.x;
      y1 = p1 * cs01.w + y1 * cs01.z;
      y2 = p2 * cs23.y + y2 * cs23.x;
      y3 = p3 * cs23.w + y3 * cs23.z;
    }
  }
  ushort4 ov;
  ov.x = f2bf(y0); ov.y = f2bf(y1); ov.z = f2bf(y2); ov.w = f2bf(y3);
  *reinterpret_cast<ushort4*>(outp + d0) = ov;
}

// ---------------- Flash attention (R5-proven inner loop, 32-row tiles) ----------------
// QBLK=32: block = 2 waves (128 thr), each wave keeps the EXACT 16-row layout
// of the proven kernel; grid (64,16) = 1024 blocks; t = 63 - blockIdx.x (LPT).
// LDS 50KB -> 3 blocks/CU (vs 2 at QBLK=64): more independent co-resident
// blocks hide barrier/DMA-drain latency (the R2 mechanism, one step further).
// K/V staging: 16 DMA insts per tile re-partitioned over 2 waves (wv*8+i).
// (R6 1-barrier and R8 setprio/raw-barrier variants regressed; 2-barrier
// structure kept verbatim.)
__global__ __launch_bounds__(128) void attn_fwd(
    const unsigned short* __restrict__ qbf,    // (T, H*D) post norm+rope
    const unsigned short* __restrict__ kbf,    // (T, KV*D) post norm+rope
    const unsigned short* __restrict__ vT,     // (KV*D, T)
    const unsigned short* __restrict__ qkvout, // (T, 9216), gate at h*512+256
    unsigned short* __restrict__ og)           // (T, H*D)
{
  const int t = 63 - (int)blockIdx.x;  // LPT: biggest tile first
  const int h = blockIdx.y;
  const int wv = threadIdx.x >> 6;     // 0,1
  const int lane = threadIdx.x & 63;
  const int lrow = lane & 15;
  const int kgrp = lane >> 4;
  const int kv = h >> 3;  // H/KV = 8
  const int q0 = t * 32 + wv * 16;
  const int nb = t + 1;   // number of 32-key blocks for this tile

  // K: [key 0..31][dim chunks swizzled: pos = c ^ (key&7)], 16KB
  __shared__ alignas(16) unsigned short Ks[32 * 256];
  // V: [dim 0..255][key chunks swizzled: pos = c ^ (dim&3)], 2x16KB
  __shared__ alignas(16) unsigned short Vs[2][256 * 32];
  // P: per-wave 16x32 bf16
  __shared__ alignas(16) unsigned short Ps[2][16 * 32];

  // DMA staging: wave wv handles insts [wv*8, wv*8+8) of 16 total per tile.
  auto stage_k = [&](int kb) {
#pragma unroll
    for (int i = 0; i < 8; ++i) {
      const int inst = wv * 8 + i;
      const int key_loc = inst * 2 + (lane >> 5);
      const int c = (lane & 31) ^ (key_loc & 7);
      const unsigned short* g =
          kbf + (size_t)(kb + key_loc) * (NKV * HD) + kv * HD + c * 8;
      gl_lds16(g, &Ks[inst * 512]);
    }
  };
  auto stage_v = [&](int kb, int buf) {
#pragma unroll
    for (int i = 0; i < 8; ++i) {
      const int inst = wv * 8 + i;
      const int dim = inst * 16 + (lane >> 2);
      const int c = (lane & 3) ^ (dim & 3);
      const unsigned short* g =
          vT + (size_t)(kv * HD + dim) * T_LEN + kb + c * 8;
      gl_lds16(g, &Vs[buf][inst * 512]);
    }
  };

  // Q A-fragments (global, once)
  bf16x8 qa[8];
  {
    const unsigned short* qr = qbf + (size_t)(q0 + lrow) * (NH * HD) + h * HD + kgrp * 8;
#pragma unroll
    for (int s = 0; s < 8; s++)
      qa[s] = *reinterpret_cast<const bf16x8*>(qr + s * 32);
  }

  float lp[4] = {0.f, 0.f, 0.f, 0.f};
  floatx4 o[16];
#pragma unroll
  for (int dt = 0; dt < 16; dt++) o[dt] = floatx4{0.f, 0.f, 0.f, 0.f};

  stage_k(0);
  stage_v(0, 0);

  for (int ib = 0; ib < nb; ++ib) {
    const int kb = ib * 32;
    __syncthreads();  // drains K(ib) + V(ib) DMAs; protects V buffer reuse
    if (ib + 1 < nb) stage_v(kb + 32, (ib + 1) & 1);

    const bool d = kb <= q0 + 15;

    // ---- S = Q K^T over 2 j-subtiles of 16 keys ----
    floatx4 s0[2];
#pragma unroll
    for (int j = 0; j < 2; j++) s0[j] = floatx4{0.f, 0.f, 0.f, 0.f};
#pragma unroll
    for (int j = 0; j < 2; ++j) {
      const int ks = kb + j * 16;
      if (!(d && (ks <= q0 + 15))) continue;
      bf16x8 kf[8];
#pragma unroll
      for (int s = 0; s < 8; s++)
        kf[s] = *reinterpret_cast<const bf16x8*>(
            &Ks[(j * 16 + lrow) * 256 + (((s * 4 + kgrp) ^ (lrow & 7)) * 8)]);
#pragma unroll
      for (int s = 0; s < 8; s++) s0[j] = mfma16(qa[s], kf[s], s0[j]);
    }

    // ---- P = exp(S*scale) with causal mask (no max subtraction) ----
    if (d) {
#pragma unroll
      for (int r = 0; r < 4; ++r) {
        const int qr = q0 + kgrp * 4 + r;
        float p0 = (kb + lrow <= qr) ? __expf(s0[0][r] * SCALE_F) : 0.f;
        float p1 = (kb + 16 + lrow <= qr) ? __expf(s0[1][r] * SCALE_F) : 0.f;
        lp[r] += p0 + p1;
        Ps[wv][(kgrp * 4 + r) * 32 + lrow] = f2bf(p0);
        Ps[wv][(kgrp * 4 + r) * 32 + 16 + lrow] = f2bf(p1);
      }
    }

    __syncthreads();  // all waves done reading Ks (also drains V(ib+1) DMA)
    if (ib + 1 < nb) stage_k(kb + 32);

    // ---- O += P V ----
    if (d) {
      bf16x8 pa = *reinterpret_cast<const bf16x8*>(&Ps[wv][lrow * 32 + kgrp * 8]);
      const unsigned short* vsb = &Vs[ib & 1][0];
#pragma unroll
      for (int dt = 0; dt < 16; ++dt) {
        const int dd = dt * 16 + lrow;
        bf16x8 bv = *reinterpret_cast<const bf16x8*>(
            &vsb[dd * 32 + ((kgrp ^ (lrow & 3)) * 8)]);
        o[dt] = mfma16(pa, bv, o[dt]);
      }
    }
  }

  // ---- reduce l across the 16 row-lanes ----
#pragma unroll
  for (int r = 0; r < 4; ++r) {
#pragma unroll
    for (int m = 8; m >= 1; m >>= 1) lp[r] += __shfl_xor(lp[r], m);
  }

  // ---- epilogue: o/l * sigmoid(gate) ----
#pragma unroll
  for (int r = 0; r < 4; ++r) {
    const int row = q0 + kgrp * 4 + r;
    const float inv_l = 1.0f / lp[r];
    const unsigned short* grow = qkvout + (size_t)row * 9216 + h * 512 + 256;
    unsigned short* orow = og + (size_t)row * (NH * HD) + h * HD;
#pragma unroll
    for (int dt = 0; dt < 16; dt++) {
      int dim = dt * 16 + lrow;
      float g = bf2f(grow[dim]);
      float val = o[dt][r] * inv_l;
      val *= 1.0f / (1.0f + __expf(-g));
      orow[dim] = f2bf(val);
    }
  }
}

extern "C" void kernel_launch(void* const* d_in, const int* in_sizes, int n_in,
                              void* d_out, int out_size, void* d_ws, size_t ws_size,
                              hipStream_t stream) {
  const int* positions = (const int*)d_in[0];
  const float* hidden = (const float*)d_in[1];
  const float* wq = (const float*)d_in[2];
  const float* wk = (const float*)d_in[3];
  const float* wv = (const float*)d_in[4];
  const float* wo = (const float*)d_in[5];
  const float* qnw = (const float*)d_in[6];
  const float* knw = (const float*)d_in[7];
  float* out = (float*)d_out;

  char* ws = (char*)d_ws;
  size_t off = 0;
  auto alloc = [&](size_t elems) -> unsigned short* {
    unsigned short* p = (unsigned short*)(ws + off);
    off += (elems * 2 + 255) & ~(size_t)255;
    return p;
  };
  unsigned short* hsb    = alloc((size_t)T_LEN * HID_DIM);
  unsigned short* qkvwb  = alloc((size_t)9216 * HID_DIM);
  unsigned short* wob    = alloc((size_t)HID_DIM * NH * HD);
  unsigned short* qkvout = alloc((size_t)T_LEN * 9216);
  unsigned short* qbf    = alloc((size_t)T_LEN * NH * HD);
  unsigned short* kbf    = alloc((size_t)T_LEN * NKV * HD);
  unsigned short* vTb    = alloc((size_t)NKV * HD * T_LEN);
  unsigned short* og     = alloc((size_t)T_LEN * NH * HD);
  float2* ropetab = (float2*)alloc((size_t)T_LEN * 32 * 4);  // 512KB, past og
  // split-K partials (2 x 2048x2048 fp32 = 33.5MB) alias hsb+qkvwb (46MB),
  // which are dead after GEMM1. GEMM2 reads og/wob only - no overlap.
  float* part = (float*)ws;

  // cvt (30720 blocks) + RoPE table tail (256 blocks)
  cvt_all<<<30976, 256, 0, stream>>>(hidden, wq, wk, wv, wo, hsb, qkvwb, wob,
                                     positions, ropetab);

  // GEMM1 writes Q/K/gate to qkvout; V columns (>=8704) go transposed
  // straight to vTb (fused vtrans).
  gemm_bf16_bt<<<dim3(72, 16, 1), 256, 0, stream>>>(hsb, qkvwb, qkvout, 2048, 9216, 2048, 2048, 1, vTb);

  // fused Q+K norm/rope: wave-local, trig-free, no barriers
  norm_rope_fused<<<dim3(T_LEN, 5), 256, 0, stream>>>(qkvout, qnw, knw, ropetab, qbf, kbf);

  // 32-row q-tiles: 1024 blocks of 128 threads, 3 blocks/CU
  attn_fwd<<<dim3(64, NH), 128, 0, stream>>>(qbf, kbf, vTb, qkvout, og);

  // split-K=2: grid.z=2 -> 512 blocks (2/CU) instead of 256 (1/CU);
  // each z writes an fp32 partial over K-half 2048.
  gemm_bf16_bt<<<dim3(16, 16, 2), 256, 0, stream>>>(og, wob, part, 2048, 2048, 4096, 2048, 0, nullptr);
  add_out<<<4096, 256, 0, stream>>>(part, out, 1048576);
}

// Round 11
// 439.663 us; speedup vs baseline: 1.1399x; 1.1399x over previous
//
#include <hip/hip_runtime.h>
#include <hip/hip_bf16.h>

#define T_LEN 2048
#define HID_DIM 2048
#define NH 16
#define NKV 2
#define HD 256
#define ROT 64
#define EPS_F 1e-6f
#define SCALE_F 0.0625f   // 256^-0.5
#define THETA_F 10000000.0f

typedef __bf16 bf16x8 __attribute__((ext_vector_type(8)));
typedef float floatx4 __attribute__((ext_vector_type(4)));

__device__ __forceinline__ unsigned short f2bf(float x) {
  unsigned int u = __float_as_uint(x);
  unsigned int rounding = 0x7FFFu + ((u >> 16) & 1u);
  return (unsigned short)((u + rounding) >> 16);
}
__device__ __forceinline__ float bf2f(unsigned short u) {
  return __uint_as_float(((unsigned int)u) << 16);
}
__device__ __forceinline__ floatx4 mfma16(bf16x8 a, bf16x8 b, floatx4 c) {
  return __builtin_amdgcn_mfma_f32_16x16x32_bf16(a, b, c, 0, 0, 0);
}
// async global->LDS DMA, 16B/lane: lds dest = wave-uniform base + lane*16
__device__ __forceinline__ void gl_lds16(const unsigned short* g, unsigned short* l) {
  __builtin_amdgcn_global_load_lds(
      (const __attribute__((address_space(1))) unsigned int*)g,
      (__attribute__((address_space(3))) unsigned int*)l, 16, 0, 0);
}

// ---------------- merged fp32 -> bf16 conversion + RoPE table ----------------
// Segments 0-4: f4-vectorized cast (7864320 float4). Tail blocks (i >=
// 7864320): one (t,i) RoPE cos/sin entry each -- 65,536 trig sets, 36x fewer
// than per-head recompute; folded here to save a launch.
__global__ __launch_bounds__(256) void cvt_all(
    const float* __restrict__ hs, const float* __restrict__ wq,
    const float* __restrict__ wk, const float* __restrict__ wv,
    const float* __restrict__ wo, unsigned short* __restrict__ hsb,
    unsigned short* __restrict__ qkvwb, unsigned short* __restrict__ wob,
    const int* __restrict__ pos, float2* __restrict__ tab) {
  int i = blockIdx.x * 256 + threadIdx.x;
  if (i >= 7864320) {
    const int tid = i - 7864320;  // t*32 + fi
    const int t = tid >> 5, fi = tid & 31;
    // theta^(-fi/32) = 2^(-fi*log2(theta)/32), log2(1e7)=23.2534966642
    const float fr = (float)pos[t] * exp2f(-(float)fi * (23.2534966642f / 32.0f));
    tab[tid] = make_float2(cosf(fr), sinf(fr));
    return;
  }
  const float4* s4;
  ushort4* d4;
  int j;
  if (i < 1048576) { s4 = (const float4*)hs; d4 = (ushort4*)hsb; j = i; }
  else if (i < 5242880) { s4 = (const float4*)wq; d4 = (ushort4*)qkvwb; j = i - 1048576; }
  else if (i < 5505024) { s4 = (const float4*)wk; d4 = (ushort4*)qkvwb + 4194304; j = i - 5242880; }
  else if (i < 5767168) { s4 = (const float4*)wv; d4 = (ushort4*)qkvwb + 4456448; j = i - 5505024; }
  else { s4 = (const float4*)wo; d4 = (ushort4*)wob; j = i - 5767168; }
  float4 v = s4[j];
  ushort4 o;
  o.x = f2bf(v.x); o.y = f2bf(v.y); o.z = f2bf(v.z); o.w = f2bf(v.w);
  d4[j] = o;
}

// ---------------- bf16 GEMM: C[M,N] = A[M,K] * B[N,K]^T ----------------
// ld = row stride of A and B (elements); Ksub = K-range per z-slice.
// blockIdx.z selects K-slice [z*Ksub, (z+1)*Ksub); fp32 path writes partial
// z to {Cv (z<2) | Cv2 (z>=2)} + (z&1)*M*N (split-K for TLP when the output
// grid alone gives < 2 blocks/CU).
// 2-phase double-buffered staging: stage tile k+1 into buf^1 BEFORE computing
// tile k from buf, one barrier per iteration.
// vTout (bf16 path only): blocks with n0 >= 8704 write their output
// TRANSPOSED to vTout[(col-8704)*T + row] (fused V transpose).
__global__ __launch_bounds__(256) void gemm_bf16_bt(
    const unsigned short* __restrict__ A,
    const unsigned short* __restrict__ B,
    void* __restrict__ Cv, void* __restrict__ Cv2, int M, int N, int ld,
    int Ksub, int c_bf16, unsigned short* __restrict__ vTout) {
  __shared__ alignas(16) unsigned short As[2][128 * 32];
  __shared__ alignas(16) unsigned short Bs[2][128 * 32];
  const int tid = threadIdx.x;
  const int m0 = blockIdx.y * 128;
  const int n0 = blockIdx.x * 128;
  const int koff = blockIdx.z * Ksub;
  const int lane = tid & 63;
  const int wave = tid >> 6;
  const int wm = (wave >> 1) * 64;
  const int wn = (wave & 1) * 64;
  const int lrow = lane & 15;
  const int kgrp = lane >> 4;

  const unsigned short* aG = A + (size_t)(m0 + wave * 32 + (lane >> 2)) * ld + (lane & 3) * 8 + koff;
  const unsigned short* bG = B + (size_t)(n0 + wave * 32 + (lane >> 2)) * ld + (lane & 3) * 8 + koff;

  auto stage = [&](int k0, int b) {
    gl_lds16(aG + k0, &As[b][(wave * 32) * 32]);
    gl_lds16(aG + (size_t)16 * ld + k0, &As[b][(wave * 32 + 16) * 32]);
    gl_lds16(bG + k0, &Bs[b][(wave * 32) * 32]);
    gl_lds16(bG + (size_t)16 * ld + k0, &Bs[b][(wave * 32 + 16) * 32]);
  };

  floatx4 acc[4][4];
#pragma unroll
  for (int i = 0; i < 4; i++)
#pragma unroll
    for (int j = 0; j < 4; j++) acc[i][j] = floatx4{0.f, 0.f, 0.f, 0.f};

  stage(0, 0);
  __syncthreads();  // buf0 ready (vmcnt(0) drain emitted before barrier)
  int cur = 0;
  for (int k0 = 0; k0 < Ksub; k0 += 32) {
    if (k0 + 32 < Ksub) stage(k0 + 32, cur ^ 1);  // in flight during compute
    bf16x8 af[4], bfr[4];
#pragma unroll
    for (int i = 0; i < 4; i++)
      af[i] = *reinterpret_cast<const bf16x8*>(&As[cur][(wm + i * 16 + lrow) * 32 + kgrp * 8]);
#pragma unroll
    for (int j = 0; j < 4; j++)
      bfr[j] = *reinterpret_cast<const bf16x8*>(&Bs[cur][(wn + j * 16 + lrow) * 32 + kgrp * 8]);
#pragma unroll
    for (int i = 0; i < 4; i++)
#pragma unroll
      for (int j = 0; j < 4; j++)
        acc[i][j] = mfma16(af[i], bfr[j], acc[i][j]);
    __syncthreads();  // drains next-tile DMA; readers of cur are done (lgkmcnt0)
    cur ^= 1;
  }

  if (c_bf16) {
    unsigned short* C = (unsigned short*)Cv;
    const bool vtile = (vTout != nullptr) && (n0 >= 8704);  // block-uniform
#pragma unroll
    for (int i = 0; i < 4; i++) {
      int row = m0 + wm + i * 16 + kgrp * 4;
#pragma unroll
      for (int j = 0; j < 4; j++) {
        int col = n0 + wn + j * 16 + lrow;
        if (vtile) {
          unsigned short* vrow = vTout + (size_t)(col - 8704) * T_LEN + row;
#pragma unroll
          for (int r = 0; r < 4; r++) vrow[r] = f2bf(acc[i][j][r]);
        } else {
#pragma unroll
          for (int r = 0; r < 4; r++)
            C[(size_t)(row + r) * N + col] = f2bf(acc[i][j][r]);
        }
      }
    }
  } else {
    float* base = (blockIdx.z < 2) ? (float*)Cv : (float*)Cv2;
    float* C = base + (size_t)(blockIdx.z & 1) * M * N;
#pragma unroll
    for (int i = 0; i < 4; i++) {
      int row = m0 + wm + i * 16 + kgrp * 4;
#pragma unroll
      for (int j = 0; j < 4; j++) {
        int col = n0 + wn + j * 16 + lrow;
#pragma unroll
        for (int r = 0; r < 4; r++)
          C[(size_t)(row + r) * N + col] = acc[i][j][r];
      }
    }
  }
}

// ---------------- sum of 4 split-K fp32 partials (2 per base) ----------------
__global__ __launch_bounds__(256) void add_out(
    const float* __restrict__ p0, const float* __restrict__ p1,
    float* __restrict__ out, int n4) {
  int i = blockIdx.x * 256 + threadIdx.x;  // float4 index
  if (i >= n4) return;
  float4 a = ((const float4*)p0)[i];
  float4 b = ((const float4*)p0)[i + n4];
  float4 c = ((const float4*)p1)[i];
  float4 d = ((const float4*)p1)[i + n4];
  float4 o;
  o.x = (a.x + b.x) + (c.x + d.x);
  o.y = (a.y + b.y) + (c.y + d.y);
  o.z = (a.z + b.z) + (c.z + d.z);
  o.w = (a.w + b.w) + (c.w + d.w);
  ((float4*)out)[i] = o;
}

// ---------------- fused RMSNorm + partial RoPE, wave-local, table-driven ----------------
// One WAVE per (t, head): 64 lanes x 4 elems (d = lane*4..lane*4+3), ushort4
// loads, pure shfl reduction -- no LDS, no __syncthreads, no on-device trig.
// grid (T, 5): y<4 -> Q heads y*4+wave; y==4 -> K kv-heads on waves 0,1.
// RoPE: lane's 4 elems are on the same side of the 32-split; partner
// (d +/- 32) lives in lane^8 (lanes 0..15 only, all active for the shfl).
__global__ __launch_bounds__(256) void norm_rope_fused(
    const unsigned short* __restrict__ qkv, const float* __restrict__ qw,
    const float* __restrict__ kw, const float2* __restrict__ tab,
    unsigned short* __restrict__ qbf, unsigned short* __restrict__ kbf) {
  const int t = blockIdx.x;
  const int y = blockIdx.y;
  const int wv = threadIdx.x >> 6;
  const int lane = threadIdx.x & 63;
  const unsigned short* in;
  const float* w;
  unsigned short* outp;
  if (y < 4) {
    const int h = y * 4 + wv;
    in = qkv + (size_t)t * 9216 + h * 512;
    w = qw;
    outp = qbf + (size_t)t * (NH * HD) + h * HD;
  } else {
    if (wv >= NKV) return;
    in = qkv + (size_t)t * 9216 + 8192 + wv * HD;
    w = kw;
    outp = kbf + (size_t)t * (NKV * HD) + wv * HD;
  }
  const int d0 = lane * 4;
  ushort4 v = *reinterpret_cast<const ushort4*>(in + d0);
  float x0 = bf2f(v.x), x1 = bf2f(v.y), x2 = bf2f(v.z), x3 = bf2f(v.w);
  float ss = (x0 * x0 + x1 * x1) + (x2 * x2 + x3 * x3);
#pragma unroll
  for (int m = 32; m >= 1; m >>= 1) ss += __shfl_xor(ss, m);
  const float rms = rsqrtf(ss * (1.0f / 256.0f) + EPS_F);
  float4 w4 = *reinterpret_cast<const float4*>(w + d0);
  float y0 = x0 * rms * (1.0f + w4.x);
  float y1 = x1 * rms * (1.0f + w4.y);
  float y2 = x2 * rms * (1.0f + w4.z);
  float y3 = x3 * rms * (1.0f + w4.w);
  if (lane < 16) {
    // d0..d0+3 all < 64; partner values (d +/- 32) sit in lane^8
    float p0 = __shfl_xor(y0, 8);
    float p1 = __shfl_xor(y1, 8);
    float p2 = __shfl_xor(y2, 8);
    float p3 = __shfl_xor(y3, 8);
    const float2* trow = tab + t * 32 + (d0 & 31);  // 4 consecutive (c,s)
    float4 cs01 = *reinterpret_cast<const float4*>(trow);
    float4 cs23 = *reinterpret_cast<const float4*>(trow + 2);
    if (d0 < 32) {
      y0 = y0 * cs01.x - p0 * cs01.y;
      y1 = y1 * cs01.z - p1 * cs01.w;
      y2 = y2 * cs23.x - p2 * cs23.y;
      y3 = y3 * cs23.z - p3 * cs23.w;
    } else {
      y0 = p0 * cs01.y + y0 * cs01.x;
      y1 = p1 * cs01.w + y1 * cs01.z;
      y2 = p2 * cs23.y + y2 * cs23.x;
      y3 = p3 * cs23.w + y3 * cs23.z;
    }
  }
  ushort4 ov;
  ov.x = f2bf(y0); ov.y = f2bf(y1); ov.z = f2bf(y2); ov.w = f2bf(y3);
  *reinterpret_cast<ushort4*>(outp + d0) = ov;
}

// ---------------- Flash attention (R5/R9-proven, single-tile 64-row blocks) ----------------
// Grid (32, 16): each block owns ONE 64-row q-tile; t = 31 - blockIdx.x (LPT).
// QBLK=64 is the measured optimum: R10's QBLK=32 halved MFMA-per-staged-byte
// and regressed 64%; R6 1-barrier and R8 setprio variants also regressed.
// This exact 2-barrier structure is kept verbatim.
__global__ __launch_bounds__(256, 2) void attn_fwd(
    const unsigned short* __restrict__ qbf,    // (T, H*D) post norm+rope
    const unsigned short* __restrict__ kbf,    // (T, KV*D) post norm+rope
    const unsigned short* __restrict__ vT,     // (KV*D, T)
    const unsigned short* __restrict__ qkvout, // (T, 9216), gate at h*512+256
    unsigned short* __restrict__ og)           // (T, H*D)
{
  const int t = 31 - (int)blockIdx.x;  // LPT: biggest tile first
  const int h = blockIdx.y;
  const int wv = threadIdx.x >> 6;
  const int lane = threadIdx.x & 63;
  const int lrow = lane & 15;
  const int kgrp = lane >> 4;
  const int kv = h >> 3;  // H/KV = 8
  const int q0 = t * 64 + wv * 16;
  const int nb = t * 2 + 2;  // number of 32-key blocks for this tile

  // K: [key 0..31][dim chunks swizzled: pos = c ^ (key&7)], 16KB
  __shared__ alignas(16) unsigned short Ks[32 * 256];
  // V: [dim 0..255][key chunks swizzled: pos = c ^ (dim&3)], 2x16KB
  __shared__ alignas(16) unsigned short Vs[2][256 * 32];
  // P: per-wave 16x32 bf16
  __shared__ alignas(16) unsigned short Ps[4][16 * 32];

  // DMA staging: wave wv handles insts [wv*4, wv*4+4) of 16 total per tile.
  auto stage_k = [&](int kb) {
#pragma unroll
    for (int i = 0; i < 4; ++i) {
      const int inst = wv * 4 + i;
      const int key_loc = inst * 2 + (lane >> 5);
      const int c = (lane & 31) ^ (key_loc & 7);
      const unsigned short* g =
          kbf + (size_t)(kb + key_loc) * (NKV * HD) + kv * HD + c * 8;
      gl_lds16(g, &Ks[inst * 512]);
    }
  };
  auto stage_v = [&](int kb, int buf) {
#pragma unroll
    for (int i = 0; i < 4; ++i) {
      const int inst = wv * 4 + i;
      const int dim = inst * 16 + (lane >> 2);
      const int c = (lane & 3) ^ (dim & 3);
      const unsigned short* g =
          vT + (size_t)(kv * HD + dim) * T_LEN + kb + c * 8;
      gl_lds16(g, &Vs[buf][inst * 512]);
    }
  };

  // Q A-fragments (global, once)
  bf16x8 qa[8];
  {
    const unsigned short* qr = qbf + (size_t)(q0 + lrow) * (NH * HD) + h * HD + kgrp * 8;
#pragma unroll
    for (int s = 0; s < 8; s++)
      qa[s] = *reinterpret_cast<const bf16x8*>(qr + s * 32);
  }

  float lp[4] = {0.f, 0.f, 0.f, 0.f};
  floatx4 o[16];
#pragma unroll
  for (int dt = 0; dt < 16; dt++) o[dt] = floatx4{0.f, 0.f, 0.f, 0.f};

  stage_k(0);
  stage_v(0, 0);

  for (int ib = 0; ib < nb; ++ib) {
    const int kb = ib * 32;
    __syncthreads();  // drains K(ib) + V(ib) DMAs; protects V buffer reuse
    if (ib + 1 < nb) stage_v(kb + 32, (ib + 1) & 1);

    const bool d = kb <= q0 + 15;

    // ---- S = Q K^T over 2 j-subtiles of 16 keys ----
    floatx4 s0[2];
#pragma unroll
    for (int j = 0; j < 2; j++) s0[j] = floatx4{0.f, 0.f, 0.f, 0.f};
#pragma unroll
    for (int j = 0; j < 2; ++j) {
      const int ks = kb + j * 16;
      if (!(d && (ks <= q0 + 15))) continue;
      bf16x8 kf[8];
#pragma unroll
      for (int s = 0; s < 8; s++)
        kf[s] = *reinterpret_cast<const bf16x8*>(
            &Ks[(j * 16 + lrow) * 256 + (((s * 4 + kgrp) ^ (lrow & 7)) * 8)]);
#pragma unroll
      for (int s = 0; s < 8; s++) s0[j] = mfma16(qa[s], kf[s], s0[j]);
    }

    // ---- P = exp(S*scale) with causal mask (no max subtraction) ----
    if (d) {
#pragma unroll
      for (int r = 0; r < 4; ++r) {
        const int qr = q0 + kgrp * 4 + r;
        float p0 = (kb + lrow <= qr) ? __expf(s0[0][r] * SCALE_F) : 0.f;
        float p1 = (kb + 16 + lrow <= qr) ? __expf(s0[1][r] * SCALE_F) : 0.f;
        lp[r] += p0 + p1;
        Ps[wv][(kgrp * 4 + r) * 32 + lrow] = f2bf(p0);
        Ps[wv][(kgrp * 4 + r) * 32 + 16 + lrow] = f2bf(p1);
      }
    }

    __syncthreads();  // all waves done reading Ks (also drains V(ib+1) DMA)
    if (ib + 1 < nb) stage_k(kb + 32);

    // ---- O += P V ----
    if (d) {
      bf16x8 pa = *reinterpret_cast<const bf16x8*>(&Ps[wv][lrow * 32 + kgrp * 8]);
      const unsigned short* vsb = &Vs[ib & 1][0];
#pragma unroll
      for (int dt = 0; dt < 16; ++dt) {
        const int dd = dt * 16 + lrow;
        bf16x8 bv = *reinterpret_cast<const bf16x8*>(
            &vsb[dd * 32 + ((kgrp ^ (lrow & 3)) * 8)]);
        o[dt] = mfma16(pa, bv, o[dt]);
      }
    }
  }

  // ---- reduce l across the 16 row-lanes ----
#pragma unroll
  for (int r = 0; r < 4; ++r) {
#pragma unroll
    for (int m = 8; m >= 1; m >>= 1) lp[r] += __shfl_xor(lp[r], m);
  }

  // ---- epilogue: o/l * sigmoid(gate) ----
#pragma unroll
  for (int r = 0; r < 4; ++r) {
    const int row = q0 + kgrp * 4 + r;
    const float inv_l = 1.0f / lp[r];
    const unsigned short* grow = qkvout + (size_t)row * 9216 + h * 512 + 256;
    unsigned short* orow = og + (size_t)row * (NH * HD) + h * HD;
#pragma unroll
    for (int dt = 0; dt < 16; dt++) {
      int dim = dt * 16 + lrow;
      float g = bf2f(grow[dim]);
      float val = o[dt][r] * inv_l;
      val *= 1.0f / (1.0f + __expf(-g));
      orow[dim] = f2bf(val);
    }
  }
}

extern "C" void kernel_launch(void* const* d_in, const int* in_sizes, int n_in,
                              void* d_out, int out_size, void* d_ws, size_t ws_size,
                              hipStream_t stream) {
  const int* positions = (const int*)d_in[0];
  const float* hidden = (const float*)d_in[1];
  const float* wq = (const float*)d_in[2];
  const float* wk = (const float*)d_in[3];
  const float* wv = (const float*)d_in[4];
  const float* wo = (const float*)d_in[5];
  const float* qnw = (const float*)d_in[6];
  const float* knw = (const float*)d_in[7];
  float* out = (float*)d_out;

  char* ws = (char*)d_ws;
  size_t off = 0;
  auto alloc = [&](size_t elems) -> unsigned short* {
    unsigned short* p = (unsigned short*)(ws + off);
    off += (elems * 2 + 255) & ~(size_t)255;
    return p;
  };
  unsigned short* hsb    = alloc((size_t)T_LEN * HID_DIM);
  unsigned short* qkvwb  = alloc((size_t)9216 * HID_DIM);
  unsigned short* wob    = alloc((size_t)HID_DIM * NH * HD);
  unsigned short* qkvout = alloc((size_t)T_LEN * 9216);
  unsigned short* qbf    = alloc((size_t)T_LEN * NH * HD);
  unsigned short* kbf    = alloc((size_t)T_LEN * NKV * HD);
  unsigned short* vTb    = alloc((size_t)NKV * HD * T_LEN);
  unsigned short* og     = alloc((size_t)T_LEN * NH * HD);
  float2* ropetab = (float2*)alloc((size_t)T_LEN * 32 * 4);  // 512KB, past og
  // split-K=4 partials: z=0,1 (33.5MB) alias hsb+qkvwb (46.1MB, dead after
  // GEMM1; wob NOT overlapped). z=2,3 (33.5MB) alias qkvout (37.7MB, dead
  // after attn_fwd's gate read; GEMM2 runs strictly after attn).
  float* part01 = (float*)ws;
  float* part23 = (float*)qkvout;

  // cvt (30720 blocks) + RoPE table tail (256 blocks)
  cvt_all<<<30976, 256, 0, stream>>>(hidden, wq, wk, wv, wo, hsb, qkvwb, wob,
                                     positions, ropetab);

  // GEMM1 writes Q/K/gate to qkvout; V columns (>=8704) go transposed
  // straight to vTb (fused vtrans).
  gemm_bf16_bt<<<dim3(72, 16, 1), 256, 0, stream>>>(hsb, qkvwb, qkvout, nullptr,
                                                    2048, 9216, 2048, 2048, 1, vTb);

  // fused Q+K norm/rope: wave-local, trig-free, no barriers
  norm_rope_fused<<<dim3(T_LEN, 5), 256, 0, stream>>>(qkvout, qnw, knw, ropetab, qbf, kbf);

  // 64-row q-tiles (R9-proven): 512 blocks of 256 threads
  attn_fwd<<<dim3(32, NH), 256, 0, stream>>>(qbf, kbf, vTb, qkvout, og);

  // split-K=4: grid.z=4 -> 1024 blocks; each z covers K-quarter 1024 and
  // writes an fp32 partial.
  gemm_bf16_bt<<<dim3(16, 16, 4), 256, 0, stream>>>(og, wob, part01, part23,
                                                    2048, 2048, 4096, 1024, 0, nullptr);
  add_out<<<4096, 256, 0, stream>>>(part01, part23, out, 1048576);
}

// Round 12
// 430.092 us; speedup vs baseline: 1.1652x; 1.0223x over previous
//
#include <hip/hip_runtime.h>
#include <hip/hip_bf16.h>

#define T_LEN 2048
#define HID_DIM 2048
#define NH 16
#define NKV 2
#define HD 256
#define ROT 64
#define EPS_F 1e-6f
#define SCALE_F 0.0625f   // 256^-0.5
#define THETA_F 10000000.0f

typedef __bf16 bf16x8 __attribute__((ext_vector_type(8)));
typedef float floatx4 __attribute__((ext_vector_type(4)));

__device__ __forceinline__ unsigned short f2bf(float x) {
  unsigned int u = __float_as_uint(x);
  unsigned int rounding = 0x7FFFu + ((u >> 16) & 1u);
  return (unsigned short)((u + rounding) >> 16);
}
__device__ __forceinline__ float bf2f(unsigned short u) {
  return __uint_as_float(((unsigned int)u) << 16);
}
__device__ __forceinline__ floatx4 mfma16(bf16x8 a, bf16x8 b, floatx4 c) {
  return __builtin_amdgcn_mfma_f32_16x16x32_bf16(a, b, c, 0, 0, 0);
}
// async global->LDS DMA, 16B/lane: lds dest = wave-uniform base + lane*16
__device__ __forceinline__ void gl_lds16(const unsigned short* g, unsigned short* l) {
  __builtin_amdgcn_global_load_lds(
      (const __attribute__((address_space(1))) unsigned int*)g,
      (__attribute__((address_space(3))) unsigned int*)l, 16, 0, 0);
}

// ---------------- merged fp32 -> bf16 conversion + RoPE table ----------------
// Segments 0-4: f4-vectorized cast (7864320 float4). Tail blocks (i >=
// 7864320): one (t,i) RoPE cos/sin entry each -- 65,536 trig sets.
__global__ __launch_bounds__(256) void cvt_all(
    const float* __restrict__ hs, const float* __restrict__ wq,
    const float* __restrict__ wk, const float* __restrict__ wv,
    const float* __restrict__ wo, unsigned short* __restrict__ hsb,
    unsigned short* __restrict__ qkvwb, unsigned short* __restrict__ wob,
    const int* __restrict__ pos, float2* __restrict__ tab) {
  int i = blockIdx.x * 256 + threadIdx.x;
  if (i >= 7864320) {
    const int tid = i - 7864320;  // t*32 + fi
    const int t = tid >> 5, fi = tid & 31;
    // theta^(-fi/32) = 2^(-fi*log2(theta)/32), log2(1e7)=23.2534966642
    const float fr = (float)pos[t] * exp2f(-(float)fi * (23.2534966642f / 32.0f));
    tab[tid] = make_float2(cosf(fr), sinf(fr));
    return;
  }
  const float4* s4;
  ushort4* d4;
  int j;
  if (i < 1048576) { s4 = (const float4*)hs; d4 = (ushort4*)hsb; j = i; }
  else if (i < 5242880) { s4 = (const float4*)wq; d4 = (ushort4*)qkvwb; j = i - 1048576; }
  else if (i < 5505024) { s4 = (const float4*)wk; d4 = (ushort4*)qkvwb + 4194304; j = i - 5242880; }
  else if (i < 5767168) { s4 = (const float4*)wv; d4 = (ushort4*)qkvwb + 4456448; j = i - 5505024; }
  else { s4 = (const float4*)wo; d4 = (ushort4*)wob; j = i - 5767168; }
  float4 v = s4[j];
  ushort4 o;
  o.x = f2bf(v.x); o.y = f2bf(v.y); o.z = f2bf(v.z); o.w = f2bf(v.w);
  d4[j] = o;
}

// ---------------- bf16 GEMM: C[M,N] = A[M,K] * B[N,K]^T ----------------
// ld = row stride of A and B (elements); Ksub = K-range per z-slice.
// blockIdx.z selects K-slice; fp32 path writes partial z to
// {Cv (z<2) | Cv2 (z>=2)} + (z&1)*M*N (split-K for TLP).
// 2-phase double-buffered staging: stage tile k+1 into buf^1 BEFORE computing
// tile k from buf, one barrier per iteration.
// vTout (bf16 path only): blocks with n0 >= 8704 write their output
// TRANSPOSED to vTout[(col-8704)*T + row] (fused V transpose).
__global__ __launch_bounds__(256) void gemm_bf16_bt(
    const unsigned short* __restrict__ A,
    const unsigned short* __restrict__ B,
    void* __restrict__ Cv, void* __restrict__ Cv2, int M, int N, int ld,
    int Ksub, int c_bf16, unsigned short* __restrict__ vTout) {
  __shared__ alignas(16) unsigned short As[2][128 * 32];
  __shared__ alignas(16) unsigned short Bs[2][128 * 32];
  const int tid = threadIdx.x;
  const int m0 = blockIdx.y * 128;
  const int n0 = blockIdx.x * 128;
  const int koff = blockIdx.z * Ksub;
  const int lane = tid & 63;
  const int wave = tid >> 6;
  const int wm = (wave >> 1) * 64;
  const int wn = (wave & 1) * 64;
  const int lrow = lane & 15;
  const int kgrp = lane >> 4;

  const unsigned short* aG = A + (size_t)(m0 + wave * 32 + (lane >> 2)) * ld + (lane & 3) * 8 + koff;
  const unsigned short* bG = B + (size_t)(n0 + wave * 32 + (lane >> 2)) * ld + (lane & 3) * 8 + koff;

  auto stage = [&](int k0, int b) {
    gl_lds16(aG + k0, &As[b][(wave * 32) * 32]);
    gl_lds16(aG + (size_t)16 * ld + k0, &As[b][(wave * 32 + 16) * 32]);
    gl_lds16(bG + k0, &Bs[b][(wave * 32) * 32]);
    gl_lds16(bG + (size_t)16 * ld + k0, &Bs[b][(wave * 32 + 16) * 32]);
  };

  floatx4 acc[4][4];
#pragma unroll
  for (int i = 0; i < 4; i++)
#pragma unroll
    for (int j = 0; j < 4; j++) acc[i][j] = floatx4{0.f, 0.f, 0.f, 0.f};

  stage(0, 0);
  __syncthreads();  // buf0 ready (vmcnt(0) drain emitted before barrier)
  int cur = 0;
  for (int k0 = 0; k0 < Ksub; k0 += 32) {
    if (k0 + 32 < Ksub) stage(k0 + 32, cur ^ 1);  // in flight during compute
    bf16x8 af[4], bfr[4];
#pragma unroll
    for (int i = 0; i < 4; i++)
      af[i] = *reinterpret_cast<const bf16x8*>(&As[cur][(wm + i * 16 + lrow) * 32 + kgrp * 8]);
#pragma unroll
    for (int j = 0; j < 4; j++)
      bfr[j] = *reinterpret_cast<const bf16x8*>(&Bs[cur][(wn + j * 16 + lrow) * 32 + kgrp * 8]);
#pragma unroll
    for (int i = 0; i < 4; i++)
#pragma unroll
      for (int j = 0; j < 4; j++)
        acc[i][j] = mfma16(af[i], bfr[j], acc[i][j]);
    __syncthreads();  // drains next-tile DMA; readers of cur are done (lgkmcnt0)
    cur ^= 1;
  }

  if (c_bf16) {
    unsigned short* C = (unsigned short*)Cv;
    const bool vtile = (vTout != nullptr) && (n0 >= 8704);  // block-uniform
#pragma unroll
    for (int i = 0; i < 4; i++) {
      int row = m0 + wm + i * 16 + kgrp * 4;
#pragma unroll
      for (int j = 0; j < 4; j++) {
        int col = n0 + wn + j * 16 + lrow;
        if (vtile) {
          unsigned short* vrow = vTout + (size_t)(col - 8704) * T_LEN + row;
#pragma unroll
          for (int r = 0; r < 4; r++) vrow[r] = f2bf(acc[i][j][r]);
        } else {
#pragma unroll
          for (int r = 0; r < 4; r++)
            C[(size_t)(row + r) * N + col] = f2bf(acc[i][j][r]);
        }
      }
    }
  } else {
    float* base = (blockIdx.z < 2) ? (float*)Cv : (float*)Cv2;
    float* C = base + (size_t)(blockIdx.z & 1) * M * N;
#pragma unroll
    for (int i = 0; i < 4; i++) {
      int row = m0 + wm + i * 16 + kgrp * 4;
#pragma unroll
      for (int j = 0; j < 4; j++) {
        int col = n0 + wn + j * 16 + lrow;
#pragma unroll
        for (int r = 0; r < 4; r++)
          C[(size_t)(row + r) * N + col] = acc[i][j][r];
      }
    }
  }
}

// ---------------- sum of 2 split-K fp32 partials ----------------
__global__ __launch_bounds__(256) void add_out(
    const float* __restrict__ p, float* __restrict__ out, int n4) {
  int i = blockIdx.x * 256 + threadIdx.x;  // float4 index
  if (i >= n4) return;
  float4 a = ((const float4*)p)[i];
  float4 b = ((const float4*)p)[i + n4];
  float4 o;
  o.x = a.x + b.x; o.y = a.y + b.y; o.z = a.z + b.z; o.w = a.w + b.w;
  ((float4*)out)[i] = o;
}

// ---------------- K RMSNorm + partial RoPE, wave-local, table-driven ----------------
// Q's norm/rope is fused into attn_fwd's prologue; only the 2 KV heads remain.
// One WAVE per (t, kv-head): grid (T), block 128 = 2 waves.
__global__ __launch_bounds__(128) void norm_rope_k(
    const unsigned short* __restrict__ qkv, const float* __restrict__ kw,
    const float2* __restrict__ tab, unsigned short* __restrict__ kbf) {
  const int t = blockIdx.x;
  const int wv = threadIdx.x >> 6;  // kv head 0,1
  const int lane = threadIdx.x & 63;
  const unsigned short* in = qkv + (size_t)t * 9216 + 8192 + wv * HD;
  unsigned short* outp = kbf + (size_t)t * (NKV * HD) + wv * HD;
  const int d0 = lane * 4;
  ushort4 v = *reinterpret_cast<const ushort4*>(in + d0);
  float x0 = bf2f(v.x), x1 = bf2f(v.y), x2 = bf2f(v.z), x3 = bf2f(v.w);
  float ss = (x0 * x0 + x1 * x1) + (x2 * x2 + x3 * x3);
#pragma unroll
  for (int m = 32; m >= 1; m >>= 1) ss += __shfl_xor(ss, m);
  const float rms = rsqrtf(ss * (1.0f / 256.0f) + EPS_F);
  float4 w4 = *reinterpret_cast<const float4*>(kw + d0);
  float y0 = x0 * rms * (1.0f + w4.x);
  float y1 = x1 * rms * (1.0f + w4.y);
  float y2 = x2 * rms * (1.0f + w4.z);
  float y3 = x3 * rms * (1.0f + w4.w);
  if (lane < 16) {
    // d0..d0+3 all < 64; partner values (d +/- 32) sit in lane^8
    float p0 = __shfl_xor(y0, 8);
    float p1 = __shfl_xor(y1, 8);
    float p2 = __shfl_xor(y2, 8);
    float p3 = __shfl_xor(y3, 8);
    const float2* trow = tab + t * 32 + (d0 & 31);  // 4 consecutive (c,s)
    float4 cs01 = *reinterpret_cast<const float4*>(trow);
    float4 cs23 = *reinterpret_cast<const float4*>(trow + 2);
    if (d0 < 32) {
      y0 = y0 * cs01.x - p0 * cs01.y;
      y1 = y1 * cs01.z - p1 * cs01.w;
      y2 = y2 * cs23.x - p2 * cs23.y;
      y3 = y3 * cs23.z - p3 * cs23.w;
    } else {
      y0 = p0 * cs01.y + y0 * cs01.x;
      y1 = p1 * cs01.w + y1 * cs01.z;
      y2 = p2 * cs23.y + y2 * cs23.x;
      y3 = p3 * cs23.w + y3 * cs23.z;
    }
  }
  ushort4 ov;
  ov.x = f2bf(y0); ov.y = f2bf(y1); ov.z = f2bf(y2); ov.w = f2bf(y3);
  *reinterpret_cast<ushort4*>(outp + d0) = ov;
}

// ---------------- Flash attention (R5/R9-proven loop + fused Q norm/rope) ----------------
// Grid (32, 16): each block owns ONE 64-row q-tile; t = 31 - blockIdx.x (LPT).
// QBLK=64 2-barrier structure kept verbatim (R6/R8/R10 variants all regressed).
// NEW: Q RMSNorm+RoPE fused into the prologue. Fragment layout makes it cheap:
//  - row q0+lrow's dims live on lanes {lrow+16k}: full sum-of-squares via
//    shfl_xor(16) + shfl_xor(32);
//  - RoPE pair (d, d+32), d<32, is lane-local: (s=0,j) <-> (s=1,j).
// Rounding chain identical to the old qbf path (bf16 in -> fp32 -> f2bf).
__global__ __launch_bounds__(256, 2) void attn_fwd(
    const unsigned short* __restrict__ qkvout, // (T, 9216): Q h*512, gate +256, K 8192+
    const unsigned short* __restrict__ kbf,    // (T, KV*D) post norm+rope
    const unsigned short* __restrict__ vT,     // (KV*D, T)
    const float* __restrict__ qw,              // q_norm_w (D)
    const float2* __restrict__ tab,            // (T,32) rope cos/sin
    unsigned short* __restrict__ og)           // (T, H*D)
{
  const int t = 31 - (int)blockIdx.x;  // LPT: biggest tile first
  const int h = blockIdx.y;
  const int wv = threadIdx.x >> 6;
  const int lane = threadIdx.x & 63;
  const int lrow = lane & 15;
  const int kgrp = lane >> 4;
  const int kv = h >> 3;  // H/KV = 8
  const int q0 = t * 64 + wv * 16;
  const int nb = t * 2 + 2;  // number of 32-key blocks for this tile

  // K: [key 0..31][dim chunks swizzled: pos = c ^ (key&7)], 16KB
  __shared__ alignas(16) unsigned short Ks[32 * 256];
  // V: [dim 0..255][key chunks swizzled: pos = c ^ (dim&3)], 2x16KB
  __shared__ alignas(16) unsigned short Vs[2][256 * 32];
  // P: per-wave 16x32 bf16
  __shared__ alignas(16) unsigned short Ps[4][16 * 32];

  // DMA staging: wave wv handles insts [wv*4, wv*4+4) of 16 total per tile.
  auto stage_k = [&](int kb) {
#pragma unroll
    for (int i = 0; i < 4; ++i) {
      const int inst = wv * 4 + i;
      const int key_loc = inst * 2 + (lane >> 5);
      const int c = (lane & 31) ^ (key_loc & 7);
      const unsigned short* g =
          kbf + (size_t)(kb + key_loc) * (NKV * HD) + kv * HD + c * 8;
      gl_lds16(g, &Ks[inst * 512]);
    }
  };
  auto stage_v = [&](int kb, int buf) {
#pragma unroll
    for (int i = 0; i < 4; ++i) {
      const int inst = wv * 4 + i;
      const int dim = inst * 16 + (lane >> 2);
      const int c = (lane & 3) ^ (dim & 3);
      const unsigned short* g =
          vT + (size_t)(kv * HD + dim) * T_LEN + kb + c * 8;
      gl_lds16(g, &Vs[buf][inst * 512]);
    }
  };

  stage_k(0);
  stage_v(0, 0);

  // ---- Q fragments: raw load + fused RMSNorm + RoPE (in-register) ----
  bf16x8 qa[8];
  {
    const unsigned short* qr = qkvout + (size_t)(q0 + lrow) * 9216 + h * 512 + kgrp * 8;
#pragma unroll
    for (int s = 0; s < 8; s++)
      qa[s] = *reinterpret_cast<const bf16x8*>(qr + s * 32);
    unsigned short* qe = reinterpret_cast<unsigned short*>(qa);
    // qe[s*8+j] = dim (kgrp*8 + s*32 + j) of row q0+lrow
    float ss = 0.f;
#pragma unroll
    for (int e = 0; e < 64; e++) { float x = bf2f(qe[e]); ss += x * x; }
    ss += __shfl_xor(ss, 16);
    ss += __shfl_xor(ss, 32);
    const float rms = rsqrtf(ss * (1.0f / 256.0f) + EPS_F);
    const float2* trow = tab + (size_t)(q0 + lrow) * 32;
#pragma unroll
    for (int j = 0; j < 8; j++) {
      const int dlo = kgrp * 8 + j;  // < 32
      float ylo = bf2f(qe[j]) * rms * (1.0f + qw[dlo]);
      float yhi = bf2f(qe[8 + j]) * rms * (1.0f + qw[dlo + 32]);
      float2 cs = trow[dlo];
      qe[j] = f2bf(ylo * cs.x - yhi * cs.y);
      qe[8 + j] = f2bf(yhi * cs.x + ylo * cs.y);
    }
#pragma unroll
    for (int s = 2; s < 8; s++)
#pragma unroll
      for (int j = 0; j < 8; j++) {
        const int d = kgrp * 8 + s * 32 + j;
        qe[s * 8 + j] = f2bf(bf2f(qe[s * 8 + j]) * rms * (1.0f + qw[d]));
      }
  }

  float lp[4] = {0.f, 0.f, 0.f, 0.f};
  floatx4 o[16];
#pragma unroll
  for (int dt = 0; dt < 16; dt++) o[dt] = floatx4{0.f, 0.f, 0.f, 0.f};

  for (int ib = 0; ib < nb; ++ib) {
    const int kb = ib * 32;
    __syncthreads();  // drains K(ib) + V(ib) DMAs; protects V buffer reuse
    if (ib + 1 < nb) stage_v(kb + 32, (ib + 1) & 1);

    const bool d = kb <= q0 + 15;

    // ---- S = Q K^T over 2 j-subtiles of 16 keys ----
    floatx4 s0[2];
#pragma unroll
    for (int j = 0; j < 2; j++) s0[j] = floatx4{0.f, 0.f, 0.f, 0.f};
#pragma unroll
    for (int j = 0; j < 2; ++j) {
      const int ks = kb + j * 16;
      if (!(d && (ks <= q0 + 15))) continue;
      bf16x8 kf[8];
#pragma unroll
      for (int s = 0; s < 8; s++)
        kf[s] = *reinterpret_cast<const bf16x8*>(
            &Ks[(j * 16 + lrow) * 256 + (((s * 4 + kgrp) ^ (lrow & 7)) * 8)]);
#pragma unroll
      for (int s = 0; s < 8; s++) s0[j] = mfma16(qa[s], kf[s], s0[j]);
    }

    // ---- P = exp(S*scale) with causal mask (no max subtraction) ----
    if (d) {
#pragma unroll
      for (int r = 0; r < 4; ++r) {
        const int qr = q0 + kgrp * 4 + r;
        float p0 = (kb + lrow <= qr) ? __expf(s0[0][r] * SCALE_F) : 0.f;
        float p1 = (kb + 16 + lrow <= qr) ? __expf(s0[1][r] * SCALE_F) : 0.f;
        lp[r] += p0 + p1;
        Ps[wv][(kgrp * 4 + r) * 32 + lrow] = f2bf(p0);
        Ps[wv][(kgrp * 4 + r) * 32 + 16 + lrow] = f2bf(p1);
      }
    }

    __syncthreads();  // all waves done reading Ks (also drains V(ib+1) DMA)
    if (ib + 1 < nb) stage_k(kb + 32);

    // ---- O += P V ----
    if (d) {
      bf16x8 pa = *reinterpret_cast<const bf16x8*>(&Ps[wv][lrow * 32 + kgrp * 8]);
      const unsigned short* vsb = &Vs[ib & 1][0];
#pragma unroll
      for (int dt = 0; dt < 16; ++dt) {
        const int dd = dt * 16 + lrow;
        bf16x8 bv = *reinterpret_cast<const bf16x8*>(
            &vsb[dd * 32 + ((kgrp ^ (lrow & 3)) * 8)]);
        o[dt] = mfma16(pa, bv, o[dt]);
      }
    }
  }

  // ---- reduce l across the 16 row-lanes ----
#pragma unroll
  for (int r = 0; r < 4; ++r) {
#pragma unroll
    for (int m = 8; m >= 1; m >>= 1) lp[r] += __shfl_xor(lp[r], m);
  }

  // ---- epilogue: o/l * sigmoid(gate) ----
#pragma unroll
  for (int r = 0; r < 4; ++r) {
    const int row = q0 + kgrp * 4 + r;
    const float inv_l = 1.0f / lp[r];
    const unsigned short* grow = qkvout + (size_t)row * 9216 + h * 512 + 256;
    unsigned short* orow = og + (size_t)row * (NH * HD) + h * HD;
#pragma unroll
    for (int dt = 0; dt < 16; dt++) {
      int dim = dt * 16 + lrow;
      float g = bf2f(grow[dim]);
      float val = o[dt][r] * inv_l;
      val *= 1.0f / (1.0f + __expf(-g));
      orow[dim] = f2bf(val);
    }
  }
}

extern "C" void kernel_launch(void* const* d_in, const int* in_sizes, int n_in,
                              void* d_out, int out_size, void* d_ws, size_t ws_size,
                              hipStream_t stream) {
  const int* positions = (const int*)d_in[0];
  const float* hidden = (const float*)d_in[1];
  const float* wq = (const float*)d_in[2];
  const float* wk = (const float*)d_in[3];
  const float* wv = (const float*)d_in[4];
  const float* wo = (const float*)d_in[5];
  const float* qnw = (const float*)d_in[6];
  const float* knw = (const float*)d_in[7];
  float* out = (float*)d_out;

  char* ws = (char*)d_ws;
  size_t off = 0;
  auto alloc = [&](size_t elems) -> unsigned short* {
    unsigned short* p = (unsigned short*)(ws + off);
    off += (elems * 2 + 255) & ~(size_t)255;
    return p;
  };
  unsigned short* hsb    = alloc((size_t)T_LEN * HID_DIM);
  unsigned short* qkvwb  = alloc((size_t)9216 * HID_DIM);
  unsigned short* wob    = alloc((size_t)HID_DIM * NH * HD);
  unsigned short* qkvout = alloc((size_t)T_LEN * 9216);
  unsigned short* kbf    = alloc((size_t)T_LEN * NKV * HD);
  unsigned short* vTb    = alloc((size_t)NKV * HD * T_LEN);
  unsigned short* og     = alloc((size_t)T_LEN * NH * HD);
  float2* ropetab = (float2*)alloc((size_t)T_LEN * 32 * 4);  // 512KB
  // split-K=2 partials (33.5MB) alias hsb+qkvwb (46MB, dead after GEMM1).
  // GEMM2 reads og/wob only - no overlap.
  float* part = (float*)ws;

  // cvt (30720 blocks) + RoPE table tail (256 blocks)
  cvt_all<<<30976, 256, 0, stream>>>(hidden, wq, wk, wv, wo, hsb, qkvwb, wob,
                                     positions, ropetab);

  // GEMM1 writes Q/K/gate to qkvout; V columns (>=8704) go transposed
  // straight to vTb (fused vtrans).
  gemm_bf16_bt<<<dim3(72, 16, 1), 256, 0, stream>>>(hsb, qkvwb, qkvout, nullptr,
                                                    2048, 9216, 2048, 2048, 1, vTb);

  // K-only norm/rope (Q fused into attn): 2048 blocks x 2 waves
  norm_rope_k<<<T_LEN, 128, 0, stream>>>(qkvout, knw, ropetab, kbf);

  // 64-row q-tiles (R9-proven loop), Q norm/rope fused in prologue
  attn_fwd<<<dim3(32, NH), 256, 0, stream>>>(qkvout, kbf, vTb, qnw, ropetab, og);

  // split-K=2: grid.z=2 -> 512 blocks (2/CU); each z covers K-half 2048.
  gemm_bf16_bt<<<dim3(16, 16, 2), 256, 0, stream>>>(og, wob, part, nullptr,
                                                    2048, 2048, 4096, 2048, 0, nullptr);
  add_out<<<4096, 256, 0, stream>>>(part, out, 1048576);
}

// Round 14
// 407.793 us; speedup vs baseline: 1.2289x; 1.0547x over previous
//
#include <hip/hip_runtime.h>
#include <hip/hip_bf16.h>

#define T_LEN 2048
#define HID_DIM 2048
#define NH 16
#define NKV 2
#define HD 256
#define ROT 64
#define EPS_F 1e-6f
#define SCALE_F 0.0625f   // 256^-0.5
#define THETA_F 10000000.0f

typedef __bf16 bf16x8 __attribute__((ext_vector_type(8)));
typedef float floatx4 __attribute__((ext_vector_type(4)));

__device__ __forceinline__ unsigned short f2bf(float x) {
  unsigned int u = __float_as_uint(x);
  unsigned int rounding = 0x7FFFu + ((u >> 16) & 1u);
  return (unsigned short)((u + rounding) >> 16);
}
__device__ __forceinline__ float bf2f(unsigned short u) {
  return __uint_as_float(((unsigned int)u) << 16);
}
__device__ __forceinline__ floatx4 mfma16(bf16x8 a, bf16x8 b, floatx4 c) {
  return __builtin_amdgcn_mfma_f32_16x16x32_bf16(a, b, c, 0, 0, 0);
}
// async global->LDS DMA, 16B/lane: lds dest = wave-uniform base + lane*16
__device__ __forceinline__ void gl_lds16(const unsigned short* g, unsigned short* l) {
  __builtin_amdgcn_global_load_lds(
      (const __attribute__((address_space(1))) unsigned int*)g,
      (__attribute__((address_space(3))) unsigned int*)l, 16, 0, 0);
}

// ---------------- merged fp32 -> bf16 conversion + RoPE table ----------------
// Segments 0-4: f4-vectorized cast (7864320 float4). Tail blocks (i >=
// 7864320): one (t,i) RoPE cos/sin entry each -- 65,536 trig sets.
__global__ __launch_bounds__(256) void cvt_all(
    const float* __restrict__ hs, const float* __restrict__ wq,
    const float* __restrict__ wk, const float* __restrict__ wv,
    const float* __restrict__ wo, unsigned short* __restrict__ hsb,
    unsigned short* __restrict__ qkvwb, unsigned short* __restrict__ wob,
    const int* __restrict__ pos, float2* __restrict__ tab) {
  int i = blockIdx.x * 256 + threadIdx.x;
  if (i >= 7864320) {
    const int tid = i - 7864320;  // t*32 + fi
    const int t = tid >> 5, fi = tid & 31;
    // theta^(-fi/32) = 2^(-fi*log2(theta)/32), log2(1e7)=23.2534966642
    const float fr = (float)pos[t] * exp2f(-(float)fi * (23.2534966642f / 32.0f));
    tab[tid] = make_float2(cosf(fr), sinf(fr));
    return;
  }
  const float4* s4;
  ushort4* d4;
  int j;
  if (i < 1048576) { s4 = (const float4*)hs; d4 = (ushort4*)hsb; j = i; }
  else if (i < 5242880) { s4 = (const float4*)wq; d4 = (ushort4*)qkvwb; j = i - 1048576; }
  else if (i < 5505024) { s4 = (const float4*)wk; d4 = (ushort4*)qkvwb + 4194304; j = i - 5242880; }
  else if (i < 5767168) { s4 = (const float4*)wv; d4 = (ushort4*)qkvwb + 4456448; j = i - 5505024; }
  else { s4 = (const float4*)wo; d4 = (ushort4*)wob; j = i - 5767168; }
  float4 v = s4[j];
  ushort4 o;
  o.x = f2bf(v.x); o.y = f2bf(v.y); o.z = f2bf(v.z); o.w = f2bf(v.w);
  d4[j] = o;
}

// ---------------- bf16 GEMM: C[M,N] = A[M,K] * B[N,K]^T ----------------
// ld = row stride of A and B (elements); Ksub = K-range per z-slice.
// blockIdx.z selects K-slice; fp32 path writes partial z to
// {Cv (z<2) | Cv2 (z>=2)} + (z&1)*M*N (split-K for TLP).
// 2-phase double-buffered staging: stage tile k+1 into buf^1 BEFORE computing
// tile k from buf, one barrier per iteration.
// vTout (bf16 path only): blocks with n0 >= 8704 write their output
// TRANSPOSED to vTout[(col-8704)*T + row] (fused V transpose).
__global__ __launch_bounds__(256) void gemm_bf16_bt(
    const unsigned short* __restrict__ A,
    const unsigned short* __restrict__ B,
    void* __restrict__ Cv, void* __restrict__ Cv2, int M, int N, int ld,
    int Ksub, int c_bf16, unsigned short* __restrict__ vTout) {
  __shared__ alignas(16) unsigned short As[2][128 * 32];
  __shared__ alignas(16) unsigned short Bs[2][128 * 32];
  const int tid = threadIdx.x;
  const int m0 = blockIdx.y * 128;
  const int n0 = blockIdx.x * 128;
  const int koff = blockIdx.z * Ksub;
  const int lane = tid & 63;
  const int wave = tid >> 6;
  const int wm = (wave >> 1) * 64;
  const int wn = (wave & 1) * 64;
  const int lrow = lane & 15;
  const int kgrp = lane >> 4;

  const unsigned short* aG = A + (size_t)(m0 + wave * 32 + (lane >> 2)) * ld + (lane & 3) * 8 + koff;
  const unsigned short* bG = B + (size_t)(n0 + wave * 32 + (lane >> 2)) * ld + (lane & 3) * 8 + koff;

  auto stage = [&](int k0, int b) {
    gl_lds16(aG + k0, &As[b][(wave * 32) * 32]);
    gl_lds16(aG + (size_t)16 * ld + k0, &As[b][(wave * 32 + 16) * 32]);
    gl_lds16(bG + k0, &Bs[b][(wave * 32) * 32]);
    gl_lds16(bG + (size_t)16 * ld + k0, &Bs[b][(wave * 32 + 16) * 32]);
  };

  floatx4 acc[4][4];
#pragma unroll
  for (int i = 0; i < 4; i++)
#pragma unroll
    for (int j = 0; j < 4; j++) acc[i][j] = floatx4{0.f, 0.f, 0.f, 0.f};

  stage(0, 0);
  __syncthreads();  // buf0 ready (vmcnt(0) drain emitted before barrier)
  int cur = 0;
  for (int k0 = 0; k0 < Ksub; k0 += 32) {
    if (k0 + 32 < Ksub) stage(k0 + 32, cur ^ 1);  // in flight during compute
    bf16x8 af[4], bfr[4];
#pragma unroll
    for (int i = 0; i < 4; i++)
      af[i] = *reinterpret_cast<const bf16x8*>(&As[cur][(wm + i * 16 + lrow) * 32 + kgrp * 8]);
#pragma unroll
    for (int j = 0; j < 4; j++)
      bfr[j] = *reinterpret_cast<const bf16x8*>(&Bs[cur][(wn + j * 16 + lrow) * 32 + kgrp * 8]);
#pragma unroll
    for (int i = 0; i < 4; i++)
#pragma unroll
      for (int j = 0; j < 4; j++)
        acc[i][j] = mfma16(af[i], bfr[j], acc[i][j]);
    __syncthreads();  // drains next-tile DMA; readers of cur are done (lgkmcnt0)
    cur ^= 1;
  }

  if (c_bf16) {
    unsigned short* C = (unsigned short*)Cv;
    const bool vtile = (vTout != nullptr) && (n0 >= 8704);  // block-uniform
#pragma unroll
    for (int i = 0; i < 4; i++) {
      int row = m0 + wm + i * 16 + kgrp * 4;
#pragma unroll
      for (int j = 0; j < 4; j++) {
        int col = n0 + wn + j * 16 + lrow;
        if (vtile) {
          unsigned short* vrow = vTout + (size_t)(col - 8704) * T_LEN + row;
#pragma unroll
          for (int r = 0; r < 4; r++) vrow[r] = f2bf(acc[i][j][r]);
        } else {
#pragma unroll
          for (int r = 0; r < 4; r++)
            C[(size_t)(row + r) * N + col] = f2bf(acc[i][j][r]);
        }
      }
    }
  } else {
    float* base = (blockIdx.z < 2) ? (float*)Cv : (float*)Cv2;
    float* C = base + (size_t)(blockIdx.z & 1) * M * N;
#pragma unroll
    for (int i = 0; i < 4; i++) {
      int row = m0 + wm + i * 16 + kgrp * 4;
#pragma unroll
      for (int j = 0; j < 4; j++) {
        int col = n0 + wn + j * 16 + lrow;
#pragma unroll
        for (int r = 0; r < 4; r++)
          C[(size_t)(row + r) * N + col] = acc[i][j][r];
      }
    }
  }
}

// ---------------- sum of 2 split-K fp32 partials ----------------
__global__ __launch_bounds__(256) void add_out(
    const float* __restrict__ p, float* __restrict__ out, int n4) {
  int i = blockIdx.x * 256 + threadIdx.x;  // float4 index
  if (i >= n4) return;
  float4 a = ((const float4*)p)[i];
  float4 b = ((const float4*)p)[i + n4];
  float4 o;
  o.x = a.x + b.x; o.y = a.y + b.y; o.z = a.z + b.z; o.w = a.w + b.w;
  ((float4*)out)[i] = o;
}

// ---------------- K RMSNorm + partial RoPE, wave-local, table-driven ----------------
// Q's norm/rope is fused into attn_fwd's prologue; only the 2 KV heads remain.
// One WAVE per (t, kv-head): grid (T), block 128 = 2 waves.
__global__ __launch_bounds__(128) void norm_rope_k(
    const unsigned short* __restrict__ qkv, const float* __restrict__ kw,
    const float2* __restrict__ tab, unsigned short* __restrict__ kbf) {
  const int t = blockIdx.x;
  const int wv = threadIdx.x >> 6;  // kv head 0,1
  const int lane = threadIdx.x & 63;
  const unsigned short* in = qkv + (size_t)t * 9216 + 8192 + wv * HD;
  unsigned short* outp = kbf + (size_t)t * (NKV * HD) + wv * HD;
  const int d0 = lane * 4;
  ushort4 v = *reinterpret_cast<const ushort4*>(in + d0);
  float x0 = bf2f(v.x), x1 = bf2f(v.y), x2 = bf2f(v.z), x3 = bf2f(v.w);
  float ss = (x0 * x0 + x1 * x1) + (x2 * x2 + x3 * x3);
#pragma unroll
  for (int m = 32; m >= 1; m >>= 1) ss += __shfl_xor(ss, m);
  const float rms = rsqrtf(ss * (1.0f / 256.0f) + EPS_F);
  float4 w4 = *reinterpret_cast<const float4*>(kw + d0);
  float y0 = x0 * rms * (1.0f + w4.x);
  float y1 = x1 * rms * (1.0f + w4.y);
  float y2 = x2 * rms * (1.0f + w4.z);
  float y3 = x3 * rms * (1.0f + w4.w);
  if (lane < 16) {
    // d0..d0+3 all < 64; partner values (d +/- 32) sit in lane^8
    float p0 = __shfl_xor(y0, 8);
    float p1 = __shfl_xor(y1, 8);
    float p2 = __shfl_xor(y2, 8);
    float p3 = __shfl_xor(y3, 8);
    const float2* trow = tab + t * 32 + (d0 & 31);  // 4 consecutive (c,s)
    float4 cs01 = *reinterpret_cast<const float4*>(trow);
    float4 cs23 = *reinterpret_cast<const float4*>(trow + 2);
    if (d0 < 32) {
      y0 = y0 * cs01.x - p0 * cs01.y;
      y1 = y1 * cs01.z - p1 * cs01.w;
      y2 = y2 * cs23.x - p2 * cs23.y;
      y3 = y3 * cs23.z - p3 * cs23.w;
    } else {
      y0 = p0 * cs01.y + y0 * cs01.x;
      y1 = p1 * cs01.w + y1 * cs01.z;
      y2 = p2 * cs23.y + y2 * cs23.x;
      y3 = p3 * cs23.w + y3 * cs23.z;
    }
  }
  ushort4 ov;
  ov.x = f2bf(y0); ov.y = f2bf(y1); ov.z = f2bf(y2); ov.w = f2bf(y3);
  *reinterpret_cast<ushort4*>(outp + d0) = ov;
}

// ---------------- Flash attention (R12-proven body, balanced CU pairing) ----------------
// Grid (16 heads, 32 tile-slots). All 512 blocks are co-resident (2/CU), so
// there is NO backfill: per-CU load = sum of its 2 blocks' iterations.
// Assignment models (linear b%256, or XCD round-robin) both pair block b with
// b+256 = same head-x, tile-slot ty+16. Mapping t = ty<16 ? ty : 47-ty makes
// the pair's tiles (t, 31-t) -> per-CU load = (2t+2)+(2(31-t)+2) = 66 iters
// for EVERY CU (was: same-t pairs, max 128 vs mean 66 = ~2x makespan).
__global__ __launch_bounds__(256, 2) void attn_fwd(
    const unsigned short* __restrict__ qkvout, // (T, 9216): Q h*512, gate +256, K 8192+
    const unsigned short* __restrict__ kbf,    // (T, KV*D) post norm+rope
    const unsigned short* __restrict__ vT,     // (KV*D, T)
    const float* __restrict__ qw,              // q_norm_w (D)
    const float2* __restrict__ tab,            // (T,32) rope cos/sin
    unsigned short* __restrict__ og)           // (T, H*D)
{
  const int h = blockIdx.x;            // 16 heads
  const int ty = (int)blockIdx.y;      // 32 tile slots
  const int t = (ty < 16) ? ty : (47 - ty);  // complementary pairing
  const int wv = threadIdx.x >> 6;
  const int lane = threadIdx.x & 63;
  const int lrow = lane & 15;
  const int kgrp = lane >> 4;
  const int kv = h >> 3;  // H/KV = 8
  const int q0 = t * 64 + wv * 16;
  const int nb = t * 2 + 2;  // number of 32-key blocks for this tile

  // K: [key 0..31][dim chunks swizzled: pos = c ^ (key&7)], 16KB
  __shared__ alignas(16) unsigned short Ks[32 * 256];
  // V: [dim 0..255][key chunks swizzled: pos = c ^ (dim&3)], 2x16KB
  __shared__ alignas(16) unsigned short Vs[2][256 * 32];
  // P: per-wave 16x32 bf16
  __shared__ alignas(16) unsigned short Ps[4][16 * 32];

  // DMA staging: wave wv handles insts [wv*4, wv*4+4) of 16 total per tile.
  auto stage_k = [&](int kb) {
#pragma unroll
    for (int i = 0; i < 4; ++i) {
      const int inst = wv * 4 + i;
      const int key_loc = inst * 2 + (lane >> 5);
      const int c = (lane & 31) ^ (key_loc & 7);
      const unsigned short* g =
          kbf + (size_t)(kb + key_loc) * (NKV * HD) + kv * HD + c * 8;
      gl_lds16(g, &Ks[inst * 512]);
    }
  };
  auto stage_v = [&](int kb, int buf) {
#pragma unroll
    for (int i = 0; i < 4; ++i) {
      const int inst = wv * 4 + i;
      const int dim = inst * 16 + (lane >> 2);
      const int c = (lane & 3) ^ (dim & 3);
      const unsigned short* g =
          vT + (size_t)(kv * HD + dim) * T_LEN + kb + c * 8;
      gl_lds16(g, &Vs[buf][inst * 512]);
    }
  };

  stage_k(0);
  stage_v(0, 0);

  // ---- Q fragments: raw load + fused RMSNorm + RoPE (in-register) ----
  bf16x8 qa[8];
  {
    const unsigned short* qr = qkvout + (size_t)(q0 + lrow) * 9216 + h * 512 + kgrp * 8;
#pragma unroll
    for (int s = 0; s < 8; s++)
      qa[s] = *reinterpret_cast<const bf16x8*>(qr + s * 32);
    unsigned short* qe = reinterpret_cast<unsigned short*>(qa);
    // qe[s*8+j] = dim (kgrp*8 + s*32 + j) of row q0+lrow
    float ss = 0.f;
#pragma unroll
    for (int e = 0; e < 64; e++) { float x = bf2f(qe[e]); ss += x * x; }
    ss += __shfl_xor(ss, 16);
    ss += __shfl_xor(ss, 32);
    const float rms = rsqrtf(ss * (1.0f / 256.0f) + EPS_F);
    const float2* trow = tab + (size_t)(q0 + lrow) * 32;
#pragma unroll
    for (int j = 0; j < 8; j++) {
      const int dlo = kgrp * 8 + j;  // < 32
      float ylo = bf2f(qe[j]) * rms * (1.0f + qw[dlo]);
      float yhi = bf2f(qe[8 + j]) * rms * (1.0f + qw[dlo + 32]);
      float2 cs = trow[dlo];
      qe[j] = f2bf(ylo * cs.x - yhi * cs.y);
      qe[8 + j] = f2bf(yhi * cs.x + ylo * cs.y);
    }
#pragma unroll
    for (int s = 2; s < 8; s++)
#pragma unroll
      for (int j = 0; j < 8; j++) {
        const int d = kgrp * 8 + s * 32 + j;
        qe[s * 8 + j] = f2bf(bf2f(qe[s * 8 + j]) * rms * (1.0f + qw[d]));
      }
  }

  float lp[4] = {0.f, 0.f, 0.f, 0.f};
  floatx4 o[16];
#pragma unroll
  for (int dt = 0; dt < 16; dt++) o[dt] = floatx4{0.f, 0.f, 0.f, 0.f};

  for (int ib = 0; ib < nb; ++ib) {
    const int kb = ib * 32;
    __syncthreads();  // drains K(ib) + V(ib) DMAs; protects V buffer reuse
    if (ib + 1 < nb) stage_v(kb + 32, (ib + 1) & 1);

    const bool d = kb <= q0 + 15;

    // ---- S = Q K^T over 2 j-subtiles of 16 keys ----
    floatx4 s0[2];
#pragma unroll
    for (int j = 0; j < 2; j++) s0[j] = floatx4{0.f, 0.f, 0.f, 0.f};
#pragma unroll
    for (int j = 0; j < 2; ++j) {
      const int ks = kb + j * 16;
      if (!(d && (ks <= q0 + 15))) continue;
      bf16x8 kf[8];
#pragma unroll
      for (int s = 0; s < 8; s++)
        kf[s] = *reinterpret_cast<const bf16x8*>(
            &Ks[(j * 16 + lrow) * 256 + (((s * 4 + kgrp) ^ (lrow & 7)) * 8)]);
#pragma unroll
      for (int s = 0; s < 8; s++) s0[j] = mfma16(qa[s], kf[s], s0[j]);
    }

    // ---- P = exp(S*scale) with causal mask (no max subtraction) ----
    if (d) {
#pragma unroll
      for (int r = 0; r < 4; ++r) {
        const int qr = q0 + kgrp * 4 + r;
        float p0 = (kb + lrow <= qr) ? __expf(s0[0][r] * SCALE_F) : 0.f;
        float p1 = (kb + 16 + lrow <= qr) ? __expf(s0[1][r] * SCALE_F) : 0.f;
        lp[r] += p0 + p1;
        Ps[wv][(kgrp * 4 + r) * 32 + lrow] = f2bf(p0);
        Ps[wv][(kgrp * 4 + r) * 32 + 16 + lrow] = f2bf(p1);
      }
    }

    __syncthreads();  // all waves done reading Ks (also drains V(ib+1) DMA)
    if (ib + 1 < nb) stage_k(kb + 32);

    // ---- O += P V ----
    if (d) {
      bf16x8 pa = *reinterpret_cast<const bf16x8*>(&Ps[wv][lrow * 32 + kgrp * 8]);
      const unsigned short* vsb = &Vs[ib & 1][0];
#pragma unroll
      for (int dt = 0; dt < 16; ++dt) {
        const int dd = dt * 16 + lrow;
        bf16x8 bv = *reinterpret_cast<const bf16x8*>(
            &vsb[dd * 32 + ((kgrp ^ (lrow & 3)) * 8)]);
        o[dt] = mfma16(pa, bv, o[dt]);
      }
    }
  }

  // ---- reduce l across the 16 row-lanes ----
#pragma unroll
  for (int r = 0; r < 4; ++r) {
#pragma unroll
    for (int m = 8; m >= 1; m >>= 1) lp[r] += __shfl_xor(lp[r], m);
  }

  // ---- epilogue: o/l * sigmoid(gate) ----
#pragma unroll
  for (int r = 0; r < 4; ++r) {
    const int row = q0 + kgrp * 4 + r;
    const float inv_l = 1.0f / lp[r];
    const unsigned short* grow = qkvout + (size_t)row * 9216 + h * 512 + 256;
    unsigned short* orow = og + (size_t)row * (NH * HD) + h * HD;
#pragma unroll
    for (int dt = 0; dt < 16; dt++) {
      int dim = dt * 16 + lrow;
      float g = bf2f(grow[dim]);
      float val = o[dt][r] * inv_l;
      val *= 1.0f / (1.0f + __expf(-g));
      orow[dim] = f2bf(val);
    }
  }
}

extern "C" void kernel_launch(void* const* d_in, const int* in_sizes, int n_in,
                              void* d_out, int out_size, void* d_ws, size_t ws_size,
                              hipStream_t stream) {
  const int* positions = (const int*)d_in[0];
  const float* hidden = (const float*)d_in[1];
  const float* wq = (const float*)d_in[2];
  const float* wk = (const float*)d_in[3];
  const float* wv = (const float*)d_in[4];
  const float* wo = (const float*)d_in[5];
  const float* qnw = (const float*)d_in[6];
  const float* knw = (const float*)d_in[7];
  float* out = (float*)d_out;

  char* ws = (char*)d_ws;
  size_t off = 0;
  auto alloc = [&](size_t elems) -> unsigned short* {
    unsigned short* p = (unsigned short*)(ws + off);
    off += (elems * 2 + 255) & ~(size_t)255;
    return p;
  };
  unsigned short* hsb    = alloc((size_t)T_LEN * HID_DIM);
  unsigned short* qkvwb  = alloc((size_t)9216 * HID_DIM);
  unsigned short* wob    = alloc((size_t)HID_DIM * NH * HD);
  unsigned short* qkvout = alloc((size_t)T_LEN * 9216);
  unsigned short* kbf    = alloc((size_t)T_LEN * NKV * HD);
  unsigned short* vTb    = alloc((size_t)NKV * HD * T_LEN);
  unsigned short* og     = alloc((size_t)T_LEN * NH * HD);
  float2* ropetab = (float2*)alloc((size_t)T_LEN * 32 * 4);  // 512KB
  // split-K=2 partials (33.5MB) alias hsb+qkvwb (46MB, dead after GEMM1).
  // GEMM2 reads og/wob only - no overlap.
  float* part = (float*)ws;

  // cvt (30720 blocks) + RoPE table tail (256 blocks)
  cvt_all<<<30976, 256, 0, stream>>>(hidden, wq, wk, wv, wo, hsb, qkvwb, wob,
                                     positions, ropetab);

  // GEMM1 writes Q/K/gate to qkvout; V columns (>=8704) go transposed
  // straight to vTb (fused vtrans).
  gemm_bf16_bt<<<dim3(72, 16, 1), 256, 0, stream>>>(hsb, qkvwb, qkvout, nullptr,
                                                    2048, 9216, 2048, 2048, 1, vTb);

  // K-only norm/rope (Q fused into attn): 2048 blocks x 2 waves
  norm_rope_k<<<T_LEN, 128, 0, stream>>>(qkvout, knw, ropetab, kbf);

  // 64-row q-tiles (R12-proven loop), balanced complementary CU pairing
  attn_fwd<<<dim3(NH, 32), 256, 0, stream>>>(qkvout, kbf, vTb, qnw, ropetab, og);

  // split-K=2: grid.z=2 -> 512 blocks (2/CU); each z covers K-half 2048.
  gemm_bf16_bt<<<dim3(16, 16, 2), 256, 0, stream>>>(og, wob, part, nullptr,
                                                    2048, 2048, 4096, 2048, 0, nullptr);
  add_out<<<4096, 256, 0, stream>>>(part, out, 1048576);
}